// Round 1
// baseline (39.508 us; speedup 1.0000x reference)
//
#include <hip/hip_runtime.h>

// Problem geometry (fixed by reference):
//   x: (32, 3, 224, 224) f32, target: (32,) i32, W: (60,3,1,1) f32, b: (60,) f32
//   out: (32, 3, 224, 224) f32
#define HW    50176   // 224*224
#define HW4   12544   // HW/4 (float4 granules per channel)
#define NB    32      // batch
#define BPN   49      // blocks per sample: 12544 / 256
#define NTHR  256

// Monotone order-preserving encoding of float into uint so atomicMin/Max work.
__device__ __forceinline__ unsigned encf(float f) {
    unsigned u = __float_as_uint(f);
    return (u & 0x80000000u) ? ~u : (u | 0x80000000u);
}
__device__ __forceinline__ float decf(unsigned k) {
    unsigned u = (k & 0x80000000u) ? (k & 0x7FFFFFFFu) : ~k;
    return __uint_as_float(u);
}

__global__ __launch_bounds__(NTHR) void minmax_kernel(
    const float* __restrict__ x, const int* __restrict__ target,
    const float* __restrict__ W, const float* __restrict__ b,
    unsigned* __restrict__ wsmin, unsigned* __restrict__ wsmax)
{
    const int blk   = blockIdx.x;
    const int n     = blk / BPN;
    const int chunk = blk % BPN;
    const int idx4  = chunk * NTHR + threadIdx.x;   // [0, HW4)

    const float4* xb = (const float4*)(x + (size_t)n * 3 * HW);
    float4 x0 = xb[idx4];
    float4 x1 = xb[idx4 + HW4];
    float4 x2 = xb[idx4 + 2 * HW4];

    const int t = target[n];

    float mn[3], mx[3];
#pragma unroll
    for (int k = 0; k < 3; ++k) {
        const int oc = t * 3 + k;
        const float w0 = W[oc * 3 + 0];
        const float w1 = W[oc * 3 + 1];
        const float w2 = W[oc * 3 + 2];
        const float bk = b[oc];
        float p0 = fmaf(w0, x0.x, fmaf(w1, x1.x, fmaf(w2, x2.x, bk)));
        float p1 = fmaf(w0, x0.y, fmaf(w1, x1.y, fmaf(w2, x2.y, bk)));
        float p2 = fmaf(w0, x0.z, fmaf(w1, x1.z, fmaf(w2, x2.z, bk)));
        float p3 = fmaf(w0, x0.w, fmaf(w1, x1.w, fmaf(w2, x2.w, bk)));
        mn[k] = fminf(fminf(p0, p1), fminf(p2, p3));
        mx[k] = fmaxf(fmaxf(p0, p1), fmaxf(p2, p3));
    }

    // wave-64 butterfly reduce
#pragma unroll
    for (int off = 32; off >= 1; off >>= 1) {
#pragma unroll
        for (int k = 0; k < 3; ++k) {
            mn[k] = fminf(mn[k], __shfl_xor(mn[k], off, 64));
            mx[k] = fmaxf(mx[k], __shfl_xor(mx[k], off, 64));
        }
    }

    __shared__ float smn[4][3], smx[4][3];
    const int lane = threadIdx.x & 63;
    const int wave = threadIdx.x >> 6;
    if (lane == 0) {
#pragma unroll
        for (int k = 0; k < 3; ++k) { smn[wave][k] = mn[k]; smx[wave][k] = mx[k]; }
    }
    __syncthreads();
    if (threadIdx.x == 0) {
#pragma unroll
        for (int k = 0; k < 3; ++k) {
            float m = fminf(fminf(smn[0][k], smn[1][k]), fminf(smn[2][k], smn[3][k]));
            float M = fmaxf(fmaxf(smx[0][k], smx[1][k]), fmaxf(smx[2][k], smx[3][k]));
            atomicMin(&wsmin[n * 3 + k], encf(m));
            atomicMax(&wsmax[n * 3 + k], encf(M));
        }
    }
}

__global__ __launch_bounds__(NTHR) void apply_kernel(
    const float* __restrict__ x, const int* __restrict__ target,
    const float* __restrict__ W, const float* __restrict__ b,
    const unsigned* __restrict__ wsmin, const unsigned* __restrict__ wsmax,
    float* __restrict__ out)
{
    const int blk   = blockIdx.x;
    const int n     = blk / BPN;
    const int chunk = blk % BPN;
    const int idx4  = chunk * NTHR + threadIdx.x;

    const float4* xb = (const float4*)(x + (size_t)n * 3 * HW);
    float4 x0 = xb[idx4];
    float4 x1 = xb[idx4 + HW4];
    float4 x2 = xb[idx4 + 2 * HW4];

    const int t = target[n];

#pragma unroll
    for (int k = 0; k < 3; ++k) {
        const int oc = t * 3 + k;
        const float w0 = W[oc * 3 + 0];
        const float w1 = W[oc * 3 + 1];
        const float w2 = W[oc * 3 + 2];
        const float bk = b[oc];
        const float pmin = decf(wsmin[n * 3 + k]);
        const float pmax = decf(wsmax[n * 3 + k]);
        const float inv  = 1.0f / (pmax - pmin);

        float p0 = fmaf(w0, x0.x, fmaf(w1, x1.x, fmaf(w2, x2.x, bk)));
        float p1 = fmaf(w0, x0.y, fmaf(w1, x1.y, fmaf(w2, x2.y, bk)));
        float p2 = fmaf(w0, x0.z, fmaf(w1, x1.z, fmaf(w2, x2.z, bk)));
        float p3 = fmaf(w0, x0.w, fmaf(w1, x1.w, fmaf(w2, x2.w, bk)));

        float4 o;
        o.x = ((p0 - pmin) * inv - 0.5f) * 2.0f;
        o.y = ((p1 - pmin) * inv - 0.5f) * 2.0f;
        o.z = ((p2 - pmin) * inv - 0.5f) * 2.0f;
        o.w = ((p3 - pmin) * inv - 0.5f) * 2.0f;
        // MAX_PERTURBATION / 128.0 == 1.0 — no extra scale needed.

        float4* ob = (float4*)(out + (size_t)n * 3 * HW + (size_t)k * HW);
        ob[idx4] = o;
    }
}

extern "C" void kernel_launch(void* const* d_in, const int* in_sizes, int n_in,
                              void* d_out, int out_size, void* d_ws, size_t ws_size,
                              hipStream_t stream) {
    const float* x      = (const float*)d_in[0];
    const int*   target = (const int*)d_in[1];
    const float* W      = (const float*)d_in[2];
    const float* b      = (const float*)d_in[3];
    float*       out    = (float*)d_out;

    unsigned* wsmin = (unsigned*)d_ws;
    unsigned* wsmax = wsmin + NB * 3;

    // d_ws is poisoned once (0xAA) and never re-poisoned; init identities every call.
    hipMemsetAsync(wsmin, 0xFF, NB * 3 * sizeof(unsigned), stream);  // max key -> min identity
    hipMemsetAsync(wsmax, 0x00, NB * 3 * sizeof(unsigned), stream);  // min key -> max identity

    dim3 grid(NB * BPN);
    minmax_kernel<<<grid, NTHR, 0, stream>>>(x, target, W, b, wsmin, wsmax);
    apply_kernel<<<grid, NTHR, 0, stream>>>(x, target, W, b, wsmin, wsmax, out);
}

// Round 2
// 16.671 us; speedup vs baseline: 2.3698x; 2.3698x over previous
//
#include <hip/hip_runtime.h>

// Problem geometry (fixed by reference):
//   x: (32, 3, 224, 224) f32, target: (32,) i32, W: (60,3,1,1) f32, b: (60,) f32
//   out: (32, 3, 224, 224) f32
#define HW    50176   // 224*224
#define HW4   12544   // HW/4 (float4 granules per channel)
#define NB    32      // batch
#define BPN   49      // blocks per sample: 12544 / 256
#define NTHR  256
#define FINF  __int_as_float(0x7f800000)

// ws layout: 6 floats per block: [pmin0,pmin1,pmin2,pmax0,pmax1,pmax2]
// All 1568*6 slots are unconditionally written by kernel 1 every call -> no
// init/memset needed, deterministic across graph replays.

__global__ __launch_bounds__(NTHR) void partial_minmax_kernel(
    const float* __restrict__ x, const int* __restrict__ target,
    const float* __restrict__ W, const float* __restrict__ b,
    float* __restrict__ ws)
{
    const int blk   = blockIdx.x;
    const int n     = blk / BPN;
    const int chunk = blk % BPN;
    const int idx4  = chunk * NTHR + threadIdx.x;   // [0, HW4)

    const float4* xb = (const float4*)(x + (size_t)n * 3 * HW);
    float4 x0 = xb[idx4];
    float4 x1 = xb[idx4 + HW4];
    float4 x2 = xb[idx4 + 2 * HW4];

    const int t = target[n];

    float mn[3], mx[3];
#pragma unroll
    for (int k = 0; k < 3; ++k) {
        const int oc = t * 3 + k;
        const float w0 = W[oc * 3 + 0];
        const float w1 = W[oc * 3 + 1];
        const float w2 = W[oc * 3 + 2];
        const float bk = b[oc];
        float p0 = fmaf(w0, x0.x, fmaf(w1, x1.x, fmaf(w2, x2.x, bk)));
        float p1 = fmaf(w0, x0.y, fmaf(w1, x1.y, fmaf(w2, x2.y, bk)));
        float p2 = fmaf(w0, x0.z, fmaf(w1, x1.z, fmaf(w2, x2.z, bk)));
        float p3 = fmaf(w0, x0.w, fmaf(w1, x1.w, fmaf(w2, x2.w, bk)));
        mn[k] = fminf(fminf(p0, p1), fminf(p2, p3));
        mx[k] = fmaxf(fmaxf(p0, p1), fmaxf(p2, p3));
    }

    // wave-64 butterfly reduce
#pragma unroll
    for (int off = 32; off >= 1; off >>= 1) {
#pragma unroll
        for (int k = 0; k < 3; ++k) {
            mn[k] = fminf(mn[k], __shfl_xor(mn[k], off, 64));
            mx[k] = fmaxf(mx[k], __shfl_xor(mx[k], off, 64));
        }
    }

    __shared__ float smn[4][3], smx[4][3];
    const int lane = threadIdx.x & 63;
    const int wave = threadIdx.x >> 6;
    if (lane == 0) {
#pragma unroll
        for (int k = 0; k < 3; ++k) { smn[wave][k] = mn[k]; smx[wave][k] = mx[k]; }
    }
    __syncthreads();
    if (threadIdx.x == 0) {
        float* dst = ws + (size_t)blk * 6;
#pragma unroll
        for (int k = 0; k < 3; ++k) {
            dst[k]     = fminf(fminf(smn[0][k], smn[1][k]), fminf(smn[2][k], smn[3][k]));
            dst[k + 3] = fmaxf(fmaxf(smx[0][k], smx[1][k]), fmaxf(smx[2][k], smx[3][k]));
        }
    }
}

__global__ __launch_bounds__(NTHR) void apply_kernel(
    const float* __restrict__ x, const int* __restrict__ target,
    const float* __restrict__ W, const float* __restrict__ b,
    const float* __restrict__ ws, float* __restrict__ out)
{
    const int blk   = blockIdx.x;
    const int n     = blk / BPN;
    const int chunk = blk % BPN;
    const int idx4  = chunk * NTHR + threadIdx.x;

    // Issue the big global loads first so they overlap the partial reduction.
    const float4* xb = (const float4*)(x + (size_t)n * 3 * HW);
    float4 x0 = xb[idx4];
    float4 x1 = xb[idx4 + HW4];
    float4 x2 = xb[idx4 + 2 * HW4];

    // Reduce this sample's 49 block-partials (L2-resident, ~1.2 KB).
    __shared__ float s_min[3], s_max[3];
    if (threadIdx.x < 64) {
        const int lane = threadIdx.x;
        float mn[3] = { FINF,  FINF,  FINF};
        float mx[3] = {-FINF, -FINF, -FINF};
        if (lane < BPN) {
            const float* p = ws + (size_t)(n * BPN + lane) * 6;
#pragma unroll
            for (int k = 0; k < 3; ++k) { mn[k] = p[k]; mx[k] = p[k + 3]; }
        }
#pragma unroll
        for (int off = 32; off >= 1; off >>= 1) {
#pragma unroll
            for (int k = 0; k < 3; ++k) {
                mn[k] = fminf(mn[k], __shfl_xor(mn[k], off, 64));
                mx[k] = fmaxf(mx[k], __shfl_xor(mx[k], off, 64));
            }
        }
        if (lane == 0) {
#pragma unroll
            for (int k = 0; k < 3; ++k) { s_min[k] = mn[k]; s_max[k] = mx[k]; }
        }
    }
    __syncthreads();

    const int t = target[n];

#pragma unroll
    for (int k = 0; k < 3; ++k) {
        const int oc = t * 3 + k;
        const float w0 = W[oc * 3 + 0];
        const float w1 = W[oc * 3 + 1];
        const float w2 = W[oc * 3 + 2];
        const float bk = b[oc];
        const float pmin = s_min[k];
        const float inv  = 1.0f / (s_max[k] - pmin);

        float p0 = fmaf(w0, x0.x, fmaf(w1, x1.x, fmaf(w2, x2.x, bk)));
        float p1 = fmaf(w0, x0.y, fmaf(w1, x1.y, fmaf(w2, x2.y, bk)));
        float p2 = fmaf(w0, x0.z, fmaf(w1, x1.z, fmaf(w2, x2.z, bk)));
        float p3 = fmaf(w0, x0.w, fmaf(w1, x1.w, fmaf(w2, x2.w, bk)));

        float4 o;
        o.x = ((p0 - pmin) * inv - 0.5f) * 2.0f;
        o.y = ((p1 - pmin) * inv - 0.5f) * 2.0f;
        o.z = ((p2 - pmin) * inv - 0.5f) * 2.0f;
        o.w = ((p3 - pmin) * inv - 0.5f) * 2.0f;
        // MAX_PERTURBATION / 128.0 == 1.0 — no extra scale needed.

        float4* ob = (float4*)(out + (size_t)n * 3 * HW + (size_t)k * HW);
        ob[idx4] = o;
    }
}

extern "C" void kernel_launch(void* const* d_in, const int* in_sizes, int n_in,
                              void* d_out, int out_size, void* d_ws, size_t ws_size,
                              hipStream_t stream) {
    const float* x      = (const float*)d_in[0];
    const int*   target = (const int*)d_in[1];
    const float* W      = (const float*)d_in[2];
    const float* b      = (const float*)d_in[3];
    float*       out    = (float*)d_out;
    float*       ws     = (float*)d_ws;   // 1568 * 6 floats = 37.6 KB

    dim3 grid(NB * BPN);
    partial_minmax_kernel<<<grid, NTHR, 0, stream>>>(x, target, W, b, ws);
    apply_kernel<<<grid, NTHR, 0, stream>>>(x, target, W, b, ws, out);
}